// Round 1
// baseline (2450.029 us; speedup 1.0000x reference)
//
#include <hip/hip_runtime.h>
#include <hip/hip_bf16.h>

#define NN 524288     // nodes
#define NE 2097152    // edges
#define NS 8192       // subgraphs
#define NG 64         // groups
#define FIN 64
#define HIDDEN 128

typedef __attribute__((ext_vector_type(8))) unsigned short ushort8;

__device__ __forceinline__ unsigned short f2b(float f) {
  union { float f; unsigned int u; } c; c.f = f;
  unsigned int u = c.u;
  unsigned int r = (u + 0x7FFFu + ((u >> 16) & 1u)) >> 16;  // RNE
  return (unsigned short)r;
}
__device__ __forceinline__ float b2f(unsigned short b) {
  union { unsigned int u; float f; } c; c.u = ((unsigned int)b) << 16;
  return c.f;
}

// ---------------------------------------------------------------------------
// K1: edge scatter.  16 threads per edge, each handles a float4 of the 64-wide
// feature row.  x[src] gather is one coalesced 256B row per edge.
// ---------------------------------------------------------------------------
__global__ __launch_bounds__(256) void k_scatter(const float* __restrict__ x,
                                                 const int* __restrict__ ei,
                                                 float* __restrict__ msg,
                                                 float* __restrict__ deg) {
  int t = blockIdx.x * 256 + threadIdx.x;  // NE*16 threads exactly
  int e = t >> 4;
  int f4 = t & 15;
  int src = ei[e];
  int dst = ei[NE + e];
  float4 v = ((const float4*)(x + (size_t)src * FIN))[f4];
  float* m = msg + (size_t)dst * FIN + (f4 << 2);
  unsafeAtomicAdd(m + 0, v.x);
  unsafeAtomicAdd(m + 1, v.y);
  unsafeAtomicAdd(m + 2, v.z);
  unsafeAtomicAdd(m + 3, v.w);
  if (f4 == 0) unsafeAtomicAdd(deg + dst, 1.0f);
}

// ---------------------------------------------------------------------------
// K2: fused conv + pool.  Per block: 128 nodes.
//   A2[n][k] = [ msg[n]/max(deg,1) | x[n] ]  (K=128), staged transposed in LDS
//   as bf16 (a2T[k][n], pad 136 shorts -> 272B rows, 16B aligned).
//   h = relu(A2 @ [W_l;W_r] + b_conv), thread tile = 8 nodes x 8 cols.
//   W rows streamed from global (64KB hot in L1/L2, broadcast across lanes).
//   Pool: h -> LDS (reuse a2T buffer), segmented sum over sorted node_batch,
//   one float atomic per (segment, col) into g.
// ---------------------------------------------------------------------------
#define CB_NODES 128
__global__ __launch_bounds__(256) void k_conv(const float* __restrict__ msg,
                                              const float* __restrict__ deg,
                                              const float* __restrict__ x,
                                              const int* __restrict__ node_batch,
                                              const float* __restrict__ Wl,
                                              const float* __restrict__ Wr,
                                              const float* __restrict__ bconv,
                                              float* __restrict__ g) {
  __shared__ unsigned short smem[128 * 136];  // a2T; later reused as h[128][128]
  __shared__ int nb_s[CB_NODES];
  __shared__ float rdeg_s[CB_NODES];
  const int t = threadIdx.x;
  const int n0 = blockIdx.x * CB_NODES;

  if (t < CB_NODES) {
    nb_s[t] = node_batch[n0 + t];
    rdeg_s[t] = 1.0f / fmaxf(deg[n0 + t], 1.0f);
  }
  __syncthreads();

  // stage a2T (transposed, bf16)
  for (int it = 0; it < 64; ++it) {
    int i = it * 256 + t;
    int n = i >> 7;      // node within block
    int k = i & 127;     // feature 0..127
    float v;
    if (k < FIN) v = msg[(size_t)(n0 + n) * FIN + k] * rdeg_s[n];
    else         v = x[(size_t)(n0 + n) * FIN + (k - FIN)];
    smem[k * 136 + n] = f2b(v);
  }
  __syncthreads();

  const int tx = t & 15;   // col group: cols tx*8..+7
  const int ty = t >> 4;   // node group: nodes ty*8..+7
  const int colbase = tx << 3;

  float acc[8][8];
#pragma unroll
  for (int i = 0; i < 8; ++i)
#pragma unroll
    for (int j = 0; j < 8; ++j) acc[i][j] = 0.f;

  auto kstep = [&](int kidx, const float* row) {
    ushort8 s8 = *(const ushort8*)(smem + kidx * 136 + (ty << 3));
    float av[8];
#pragma unroll
    for (int i = 0; i < 8; ++i) av[i] = b2f((unsigned short)s8[i]);
    float4 wa = *(const float4*)(row + colbase);
    float4 wb = *(const float4*)(row + colbase + 4);
    float wv[8] = {wa.x, wa.y, wa.z, wa.w, wb.x, wb.y, wb.z, wb.w};
#pragma unroll
    for (int i = 0; i < 8; ++i)
#pragma unroll
      for (int j = 0; j < 8; ++j) acc[i][j] = fmaf(av[i], wv[j], acc[i][j]);
  };
  for (int k = 0; k < FIN; ++k) kstep(k, Wl + k * HIDDEN);
  for (int k = 0; k < FIN; ++k) kstep(FIN + k, Wr + k * HIDDEN);

  // epilogue: bias + relu, write h (bf16) back into smem as h[n][j]
  float4 ba = *(const float4*)(bconv + colbase);
  float4 bb = *(const float4*)(bconv + colbase + 4);
  float bv[8] = {ba.x, ba.y, ba.z, ba.w, bb.x, bb.y, bb.z, bb.w};

  __syncthreads();  // everyone done reading a2T before overwrite
#pragma unroll
  for (int i = 0; i < 8; ++i) {
    int n = (ty << 3) + i;
    ushort8 hv;
#pragma unroll
    for (int j = 0; j < 8; ++j) {
      float hval = fmaxf(acc[i][j] + bv[j], 0.f);
      hv[j] = f2b(hval);
    }
    *(ushort8*)(smem + n * HIDDEN + colbase) = hv;
  }
  __syncthreads();

  // segmented pool over sorted node_batch: ~1 atomic per (segment, col)
  if (t < HIDDEN) {
    int j = t;
    float sum = 0.f;
    int cur = nb_s[0];
    for (int n = 0; n < CB_NODES; ++n) {
      int b = nb_s[n];
      if (b != cur) {
        unsafeAtomicAdd(&g[(size_t)cur * HIDDEN + j], sum);
        sum = 0.f;
        cur = b;
      }
      sum += b2f(smem[n * HIDDEN + j]);
    }
    unsafeAtomicAdd(&g[(size_t)cur * HIDDEN + j], sum);
  }
}

// ---------------------------------------------------------------------------
// K3: MLP head, one wave per subgraph.  lane j computes t1[j], t1[j+64];
// wave-reduce the W2 dot; lane 0 scatters energy/norm atomics (G=64 addrs).
// ---------------------------------------------------------------------------
__global__ __launch_bounds__(256) void k_head(const float* __restrict__ g,
                                              const float* __restrict__ W1,
                                              const float* __restrict__ b1,
                                              const float* __restrict__ W2,
                                              const float* __restrict__ b2,
                                              const float* __restrict__ wts,
                                              const int* __restrict__ sgb,
                                              float* __restrict__ egy,
                                              float* __restrict__ nrm) {
  int s = blockIdx.x * 4 + (threadIdx.x >> 6);
  int lane = threadIdx.x & 63;
  const float* grow = g + (size_t)s * HIDDEN;
  float acc0 = b1[lane];
  float acc1 = b1[lane + 64];
  for (int k = 0; k < HIDDEN; ++k) {
    float gk = grow[k];  // wave-uniform
    acc0 = fmaf(gk, W1[k * HIDDEN + lane], acc0);
    acc1 = fmaf(gk, W1[k * HIDDEN + 64 + lane], acc1);
  }
  float t0 = acc0 > 0.f ? acc0 : 0.01f * acc0;
  float t1 = acc1 > 0.f ? acc1 : 0.01f * acc1;
  float part = t0 * W2[lane] + t1 * W2[lane + 64];
#pragma unroll
  for (int off = 32; off > 0; off >>= 1) part += __shfl_down(part, off, 64);
  if (lane == 0) {
    float sval = part + b2[0];
    float w = wts[s];
    int grp = sgb[s];
    unsafeAtomicAdd(&egy[grp], sval * w);
    unsafeAtomicAdd(&nrm[grp], w);
  }
}

__global__ void k_final(const float* __restrict__ egy,
                        const float* __restrict__ nrm,
                        float* __restrict__ out) {
  int t = threadIdx.x;
  out[t] = egy[t] / nrm[t];
}

// ---------------------------------------------------------------------------
extern "C" void kernel_launch(void* const* d_in, const int* in_sizes, int n_in,
                              void* d_out, int out_size, void* d_ws, size_t ws_size,
                              hipStream_t stream) {
  const float* x   = (const float*)d_in[0];
  const int*   ei  = (const int*)d_in[1];
  const int*   nb  = (const int*)d_in[2];
  const float* wts = (const float*)d_in[3];
  const int*   sgb = (const int*)d_in[4];
  const float* Wl  = (const float*)d_in[5];
  const float* Wr  = (const float*)d_in[6];
  const float* bcv = (const float*)d_in[7];
  const float* W1  = (const float*)d_in[8];
  const float* b1  = (const float*)d_in[9];
  const float* W2  = (const float*)d_in[10];
  const float* b2  = (const float*)d_in[11];
  float* out = (float*)d_out;

  // workspace layout (floats): msg[NN*64] | deg[NN] | g[NS*128] | egy[64] | nrm[64]
  float* msg = (float*)d_ws;
  float* deg = msg + (size_t)NN * FIN;
  float* g   = deg + NN;
  float* egy = g + (size_t)NS * HIDDEN;
  float* nrm = egy + NG;
  size_t zero_bytes =
      ((size_t)NN * FIN + NN + (size_t)NS * HIDDEN + 2 * NG) * sizeof(float);
  hipMemsetAsync(d_ws, 0, zero_bytes, stream);

  k_scatter<<<(NE * 16) / 256, 256, 0, stream>>>(x, ei, msg, deg);
  k_conv<<<NN / CB_NODES, 256, 0, stream>>>(msg, deg, x, nb, Wl, Wr, bcv, g);
  k_head<<<NS / 4, 256, 0, stream>>>(g, W1, b1, W2, b2, wts, sgb, egy, nrm);
  k_final<<<1, 64, 0, stream>>>(egy, nrm, out);
}

// Round 2
// 1439.412 us; speedup vs baseline: 1.7021x; 1.7021x over previous
//
#include <hip/hip_runtime.h>
#include <hip/hip_bf16.h>

#define NN 524288     // nodes
#define NE 2097152    // edges
#define NS 8192       // subgraphs
#define NG 64         // groups
#define FIN 64
#define HIDDEN 128

typedef __attribute__((ext_vector_type(8))) unsigned short ushort8;

__device__ __forceinline__ unsigned short f2b(float f) {
  union { float f; unsigned int u; } c; c.f = f;
  unsigned int u = c.u;
  unsigned int r = (u + 0x7FFFu + ((u >> 16) & 1u)) >> 16;  // RNE
  return (unsigned short)r;
}
__device__ __forceinline__ float b2f(unsigned short b) {
  union { unsigned int u; float f; } c; c.u = ((unsigned int)b) << 16;
  return c.f;
}

// ---------------------------------------------------------------------------
// CSR build: histogram -> scan -> place
// ---------------------------------------------------------------------------
__global__ __launch_bounds__(256) void k_hist(const int* __restrict__ ei,
                                              int* __restrict__ cnt) {
  int e = blockIdx.x * 256 + threadIdx.x;
  int dst = ei[NE + e];
  atomicAdd(&cnt[dst], 1);
}

// per-block exclusive scan of 256 counters; block total -> bsum
__global__ __launch_bounds__(256) void k_scan1(const int* __restrict__ cnt,
                                               int* __restrict__ rowptr,
                                               int* __restrict__ bsum) {
  __shared__ int s[256];
  int t = threadIdx.x;
  int i = blockIdx.x * 256 + t;
  int v = cnt[i];
  s[t] = v;
  __syncthreads();
  for (int off = 1; off < 256; off <<= 1) {
    int xv = 0;
    if (t >= off) xv = s[t - off];
    __syncthreads();
    s[t] += xv;
    __syncthreads();
  }
  rowptr[i] = s[t] - v;               // exclusive within block
  if (t == 255) bsum[blockIdx.x] = s[255];
}

// single block scans 2048 block sums in place (exclusive)
__global__ __launch_bounds__(256) void k_scan2(int* __restrict__ bsum) {
  __shared__ int s[256];
  __shared__ int carry_s;
  int t = threadIdx.x;
  if (t == 0) carry_s = 0;
  __syncthreads();
  for (int c = 0; c < 8; ++c) {
    int v = bsum[c * 256 + t];
    s[t] = v;
    __syncthreads();
    for (int off = 1; off < 256; off <<= 1) {
      int xv = 0;
      if (t >= off) xv = s[t - off];
      __syncthreads();
      s[t] += xv;
      __syncthreads();
    }
    int carry = carry_s;
    int incl = s[t];
    bsum[c * 256 + t] = carry + incl - v;  // exclusive + carry
    __syncthreads();
    if (t == 255) carry_s = carry + incl;
    __syncthreads();
  }
}

__global__ __launch_bounds__(256) void k_scan3(int* __restrict__ rowptr,
                                               const int* __restrict__ bsum,
                                               int* __restrict__ cursor) {
  int i = blockIdx.x * 256 + threadIdx.x;
  int rp = rowptr[i] + bsum[blockIdx.x];
  rowptr[i] = rp;
  cursor[i] = rp;
  if (i == 0) rowptr[NN] = NE;
}

__global__ __launch_bounds__(256) void k_place(const int* __restrict__ ei,
                                               int* __restrict__ cursor,
                                               int* __restrict__ bucket) {
  int e = blockIdx.x * 256 + threadIdx.x;
  int src = ei[e];
  int dst = ei[NE + e];
  int pos = atomicAdd(&cursor[dst], 1);
  bucket[pos] = src;
}

// ---------------------------------------------------------------------------
// Aggregate: per block 64 nodes, contiguous CSR edge range.  16 lanes/edge
// gather x[src] rows (256B coalesced), LDS-atomic accumulate into padded agg
// tile, write msg = agg/max(deg,1) once.  No global atomics, no msg zeroing.
// ---------------------------------------------------------------------------
#define AGG_NODES 64
__global__ __launch_bounds__(256) void k_aggregate(const float* __restrict__ x,
                                                   const int* __restrict__ rowptr,
                                                   const int* __restrict__ bucket,
                                                   float* __restrict__ msg) {
  __shared__ int rp_s[AGG_NODES + 1];
  __shared__ float agg[AGG_NODES][68];  // stride 68: 16B-aligned rows, bank-spread
  const int t = threadIdx.x;
  const int n0 = blockIdx.x * AGG_NODES;

  if (t <= AGG_NODES) rp_s[t] = rowptr[n0 + t];
  for (int i = t; i < AGG_NODES * 68; i += 256) ((float*)agg)[i] = 0.f;
  __syncthreads();

  const int e0 = rp_s[0], e1 = rp_s[AGG_NODES];
  const int lane16 = t & 15, eg = t >> 4;
  for (int eb = e0; eb < e1; eb += 16) {
    int e = eb + eg;
    if (e < e1) {
      int src = bucket[e];
      // binary search: largest n with rp_s[n] <= e
      int lo = 0, hi = AGG_NODES;
      while (hi - lo > 1) {
        int mid = (lo + hi) >> 1;
        if (rp_s[mid] <= e) lo = mid; else hi = mid;
      }
      float4 v = *(const float4*)(x + (size_t)src * FIN + lane16 * 4);
      float* arow = agg[lo] + lane16 * 4;
      atomicAdd(arow + 0, v.x);
      atomicAdd(arow + 1, v.y);
      atomicAdd(arow + 2, v.z);
      atomicAdd(arow + 3, v.w);
    }
  }
  __syncthreads();

  for (int i = t; i < AGG_NODES * 16; i += 256) {
    int n = i >> 4, q = i & 15;
    float rdeg = 1.f / fmaxf((float)(rp_s[n + 1] - rp_s[n]), 1.f);
    float4 v = *(float4*)(agg[n] + q * 4);
    v.x *= rdeg; v.y *= rdeg; v.z *= rdeg; v.w *= rdeg;
    *(float4*)(msg + (size_t)(n0 + n) * FIN + q * 4) = v;
  }
}

// ---------------------------------------------------------------------------
// K2: fused conv + pool (unchanged structure; msg now pre-divided by deg).
// ---------------------------------------------------------------------------
#define CB_NODES 128
__global__ __launch_bounds__(256) void k_conv(const float* __restrict__ msg,
                                              const float* __restrict__ x,
                                              const int* __restrict__ node_batch,
                                              const float* __restrict__ Wl,
                                              const float* __restrict__ Wr,
                                              const float* __restrict__ bconv,
                                              float* __restrict__ g) {
  __shared__ unsigned short smem[128 * 136];  // a2T; later reused as h[128][128]
  __shared__ int nb_s[CB_NODES];
  const int t = threadIdx.x;
  const int n0 = blockIdx.x * CB_NODES;

  if (t < CB_NODES) nb_s[t] = node_batch[n0 + t];
  __syncthreads();

  // stage a2T (transposed, bf16)
  for (int it = 0; it < 64; ++it) {
    int i = it * 256 + t;
    int n = i >> 7;      // node within block
    int k = i & 127;     // feature 0..127
    float v;
    if (k < FIN) v = msg[(size_t)(n0 + n) * FIN + k];
    else         v = x[(size_t)(n0 + n) * FIN + (k - FIN)];
    smem[k * 136 + n] = f2b(v);
  }
  __syncthreads();

  const int tx = t & 15;   // col group: cols tx*8..+7
  const int ty = t >> 4;   // node group: nodes ty*8..+7
  const int colbase = tx << 3;

  float acc[8][8];
#pragma unroll
  for (int i = 0; i < 8; ++i)
#pragma unroll
    for (int j = 0; j < 8; ++j) acc[i][j] = 0.f;

  auto kstep = [&](int kidx, const float* row) {
    ushort8 s8 = *(const ushort8*)(smem + kidx * 136 + (ty << 3));
    float av[8];
#pragma unroll
    for (int i = 0; i < 8; ++i) av[i] = b2f((unsigned short)s8[i]);
    float4 wa = *(const float4*)(row + colbase);
    float4 wb = *(const float4*)(row + colbase + 4);
    float wv[8] = {wa.x, wa.y, wa.z, wa.w, wb.x, wb.y, wb.z, wb.w};
#pragma unroll
    for (int i = 0; i < 8; ++i)
#pragma unroll
      for (int j = 0; j < 8; ++j) acc[i][j] = fmaf(av[i], wv[j], acc[i][j]);
  };
  for (int k = 0; k < FIN; ++k) kstep(k, Wl + k * HIDDEN);
  for (int k = 0; k < FIN; ++k) kstep(FIN + k, Wr + k * HIDDEN);

  // epilogue: bias + relu, write h (bf16) back into smem as h[n][j]
  float4 ba = *(const float4*)(bconv + colbase);
  float4 bb = *(const float4*)(bconv + colbase + 4);
  float bv[8] = {ba.x, ba.y, ba.z, ba.w, bb.x, bb.y, bb.z, bb.w};

  __syncthreads();  // everyone done reading a2T before overwrite
#pragma unroll
  for (int i = 0; i < 8; ++i) {
    int n = (ty << 3) + i;
    ushort8 hv;
#pragma unroll
    for (int j = 0; j < 8; ++j) {
      float hval = fmaxf(acc[i][j] + bv[j], 0.f);
      hv[j] = f2b(hval);
    }
    *(ushort8*)(smem + n * HIDDEN + colbase) = hv;
  }
  __syncthreads();

  // segmented pool over sorted node_batch: ~1 atomic per (segment, col)
  if (t < HIDDEN) {
    int j = t;
    float sum = 0.f;
    int cur = nb_s[0];
    for (int n = 0; n < CB_NODES; ++n) {
      int b = nb_s[n];
      if (b != cur) {
        unsafeAtomicAdd(&g[(size_t)cur * HIDDEN + j], sum);
        sum = 0.f;
        cur = b;
      }
      sum += b2f(smem[n * HIDDEN + j]);
    }
    unsafeAtomicAdd(&g[(size_t)cur * HIDDEN + j], sum);
  }
}

// ---------------------------------------------------------------------------
// K3: MLP head, one wave per subgraph.
// ---------------------------------------------------------------------------
__global__ __launch_bounds__(256) void k_head(const float* __restrict__ g,
                                              const float* __restrict__ W1,
                                              const float* __restrict__ b1,
                                              const float* __restrict__ W2,
                                              const float* __restrict__ b2,
                                              const float* __restrict__ wts,
                                              const int* __restrict__ sgb,
                                              float* __restrict__ egy,
                                              float* __restrict__ nrm) {
  int s = blockIdx.x * 4 + (threadIdx.x >> 6);
  int lane = threadIdx.x & 63;
  const float* grow = g + (size_t)s * HIDDEN;
  float acc0 = b1[lane];
  float acc1 = b1[lane + 64];
  for (int k = 0; k < HIDDEN; ++k) {
    float gk = grow[k];  // wave-uniform
    acc0 = fmaf(gk, W1[k * HIDDEN + lane], acc0);
    acc1 = fmaf(gk, W1[k * HIDDEN + 64 + lane], acc1);
  }
  float t0 = acc0 > 0.f ? acc0 : 0.01f * acc0;
  float t1 = acc1 > 0.f ? acc1 : 0.01f * acc1;
  float part = t0 * W2[lane] + t1 * W2[lane + 64];
#pragma unroll
  for (int off = 32; off > 0; off >>= 1) part += __shfl_down(part, off, 64);
  if (lane == 0) {
    float sval = part + b2[0];
    float w = wts[s];
    int grp = sgb[s];
    unsafeAtomicAdd(&egy[grp], sval * w);
    unsafeAtomicAdd(&nrm[grp], w);
  }
}

__global__ void k_final(const float* __restrict__ egy,
                        const float* __restrict__ nrm,
                        float* __restrict__ out) {
  int t = threadIdx.x;
  out[t] = egy[t] / nrm[t];
}

// ---------------------------------------------------------------------------
extern "C" void kernel_launch(void* const* d_in, const int* in_sizes, int n_in,
                              void* d_out, int out_size, void* d_ws, size_t ws_size,
                              hipStream_t stream) {
  const float* x   = (const float*)d_in[0];
  const int*   ei  = (const int*)d_in[1];
  const int*   nb  = (const int*)d_in[2];
  const float* wts = (const float*)d_in[3];
  const int*   sgb = (const int*)d_in[4];
  const float* Wl  = (const float*)d_in[5];
  const float* Wr  = (const float*)d_in[6];
  const float* bcv = (const float*)d_in[7];
  const float* W1  = (const float*)d_in[8];
  const float* b1  = (const float*)d_in[9];
  const float* W2  = (const float*)d_in[10];
  const float* b2  = (const float*)d_in[11];
  float* out = (float*)d_out;

  // ws layout (4B units), zeroed region first:
  //   cnt[NN] | g[NS*128] | egy[64] | nrm[64]   <- memset 0
  //   rowptr[NN+1] | cursor[NN] | bsum[2048] | bucket[NE] | msg[NN*64]
  int*   cnt    = (int*)d_ws;
  float* g      = (float*)(cnt + NN);
  float* egy    = g + (size_t)NS * HIDDEN;
  float* nrm    = egy + NG;
  int*   rowptr = (int*)(nrm + NG);
  int*   cursor = rowptr + NN + 1;
  int*   bsum   = cursor + NN;
  int*   bucket = bsum + 2048;
  float* msg    = (float*)(bucket + NE);

  size_t zero_bytes = ((size_t)NN + (size_t)NS * HIDDEN + 2 * NG) * 4;
  hipMemsetAsync(d_ws, 0, zero_bytes, stream);

  k_hist <<<NE / 256, 256, 0, stream>>>(ei, cnt);
  k_scan1<<<NN / 256, 256, 0, stream>>>(cnt, rowptr, bsum);
  k_scan2<<<1, 256, 0, stream>>>(bsum);
  k_scan3<<<NN / 256, 256, 0, stream>>>(rowptr, bsum, cursor);
  k_place<<<NE / 256, 256, 0, stream>>>(ei, cursor, bucket);
  k_aggregate<<<NN / AGG_NODES, 256, 0, stream>>>(x, rowptr, bucket, msg);
  k_conv<<<NN / CB_NODES, 256, 0, stream>>>(msg, x, nb, Wl, Wr, bcv, g);
  k_head<<<NS / 4, 256, 0, stream>>>(g, W1, b1, W2, b2, wts, sgb, egy, nrm);
  k_final<<<1, 64, 0, stream>>>(egy, nrm, out);
}

// Round 3
// 870.736 us; speedup vs baseline: 2.8137x; 1.6531x over previous
//
#include <hip/hip_runtime.h>
#include <hip/hip_bf16.h>

#define NN 524288     // nodes
#define NE 2097152    // edges
#define NS 8192       // subgraphs
#define NG 64         // groups
#define FIN 64
#define HIDDEN 128

typedef __attribute__((ext_vector_type(8))) unsigned short ushort8;

__device__ __forceinline__ unsigned short f2b(float f) {
  union { float f; unsigned int u; } c; c.f = f;
  unsigned int u = c.u;
  unsigned int r = (u + 0x7FFFu + ((u >> 16) & 1u)) >> 16;  // RNE
  return (unsigned short)r;
}
__device__ __forceinline__ float b2f(unsigned short b) {
  union { unsigned int u; float f; } c; c.u = ((unsigned int)b) << 16;
  return c.f;
}

// ---------------------------------------------------------------------------
// CSR build: histogram -> scan -> place
// ---------------------------------------------------------------------------
__global__ __launch_bounds__(256) void k_hist(const int* __restrict__ ei,
                                              int* __restrict__ cnt) {
  int e = blockIdx.x * 256 + threadIdx.x;
  int dst = ei[NE + e];
  atomicAdd(&cnt[dst], 1);
}

// per-block exclusive scan of 256 counters; block total -> bsum
__global__ __launch_bounds__(256) void k_scan1(const int* __restrict__ cnt,
                                               int* __restrict__ rowptr,
                                               int* __restrict__ bsum) {
  __shared__ int s[256];
  int t = threadIdx.x;
  int i = blockIdx.x * 256 + t;
  int v = cnt[i];
  s[t] = v;
  __syncthreads();
  for (int off = 1; off < 256; off <<= 1) {
    int xv = 0;
    if (t >= off) xv = s[t - off];
    __syncthreads();
    s[t] += xv;
    __syncthreads();
  }
  rowptr[i] = s[t] - v;               // exclusive within block
  if (t == 255) bsum[blockIdx.x] = s[255];
}

// single block scans 2048 block sums in place (exclusive)
__global__ __launch_bounds__(256) void k_scan2(int* __restrict__ bsum) {
  __shared__ int s[256];
  __shared__ int carry_s;
  int t = threadIdx.x;
  if (t == 0) carry_s = 0;
  __syncthreads();
  for (int c = 0; c < 8; ++c) {
    int v = bsum[c * 256 + t];
    s[t] = v;
    __syncthreads();
    for (int off = 1; off < 256; off <<= 1) {
      int xv = 0;
      if (t >= off) xv = s[t - off];
      __syncthreads();
      s[t] += xv;
      __syncthreads();
    }
    int carry = carry_s;
    int incl = s[t];
    bsum[c * 256 + t] = carry + incl - v;  // exclusive + carry
    __syncthreads();
    if (t == 255) carry_s = carry + incl;
    __syncthreads();
  }
}

__global__ __launch_bounds__(256) void k_scan3(int* __restrict__ rowptr,
                                               const int* __restrict__ bsum,
                                               int* __restrict__ cursor) {
  int i = blockIdx.x * 256 + threadIdx.x;
  int rp = rowptr[i] + bsum[blockIdx.x];
  rowptr[i] = rp;
  cursor[i] = rp;
  if (i == 0) rowptr[NN] = NE;
}

__global__ __launch_bounds__(256) void k_place(const int* __restrict__ ei,
                                               int* __restrict__ cursor,
                                               int* __restrict__ bucket) {
  int e = blockIdx.x * 256 + threadIdx.x;
  int src = ei[e];
  int dst = ei[NE + e];
  int pos = atomicAdd(&cursor[dst], 1);
  bucket[pos] = src;
}

// ---------------------------------------------------------------------------
// Aggregate v3: one node per 16-lane group, register float4 accumulation.
// No LDS, no atomics, no binary search.  Edges contiguous per node (CSR):
// group walks its range, gathering x[src] rows (256B coalesced per group).
// Unroll x2 for memory-level parallelism; 4 independent groups per wave.
// ---------------------------------------------------------------------------
__global__ __launch_bounds__(256) void k_aggregate(const float* __restrict__ x,
                                                   const int* __restrict__ rowptr,
                                                   const int* __restrict__ bucket,
                                                   float* __restrict__ msg) {
  const int t = threadIdx.x;
  const int grp = t >> 4;       // 0..15: node within block
  const int lane = t & 15;      // float4 slot within row
  const int n = blockIdx.x * 16 + grp;
  const int rp0 = rowptr[n];
  const int rp1 = rowptr[n + 1];

  float4 a0 = make_float4(0.f, 0.f, 0.f, 0.f);
  float4 a1 = make_float4(0.f, 0.f, 0.f, 0.f);
  int e = rp0;
  for (; e + 1 < rp1; e += 2) {
    int s0 = bucket[e];
    int s1 = bucket[e + 1];
    float4 v0 = *(const float4*)(x + (size_t)s0 * FIN + (lane << 2));
    float4 v1 = *(const float4*)(x + (size_t)s1 * FIN + (lane << 2));
    a0.x += v0.x; a0.y += v0.y; a0.z += v0.z; a0.w += v0.w;
    a1.x += v1.x; a1.y += v1.y; a1.z += v1.z; a1.w += v1.w;
  }
  if (e < rp1) {
    int s0 = bucket[e];
    float4 v0 = *(const float4*)(x + (size_t)s0 * FIN + (lane << 2));
    a0.x += v0.x; a0.y += v0.y; a0.z += v0.z; a0.w += v0.w;
  }
  float rdeg = 1.f / fmaxf((float)(rp1 - rp0), 1.f);
  float4 r;
  r.x = (a0.x + a1.x) * rdeg;
  r.y = (a0.y + a1.y) * rdeg;
  r.z = (a0.z + a1.z) * rdeg;
  r.w = (a0.w + a1.w) * rdeg;
  *(float4*)(msg + (size_t)n * FIN + (lane << 2)) = r;
}

// ---------------------------------------------------------------------------
// K2: fused conv + pool (msg pre-divided by deg).
// ---------------------------------------------------------------------------
#define CB_NODES 128
__global__ __launch_bounds__(256) void k_conv(const float* __restrict__ msg,
                                              const float* __restrict__ x,
                                              const int* __restrict__ node_batch,
                                              const float* __restrict__ Wl,
                                              const float* __restrict__ Wr,
                                              const float* __restrict__ bconv,
                                              float* __restrict__ g) {
  __shared__ unsigned short smem[128 * 136];  // a2T; later reused as h[128][128]
  __shared__ int nb_s[CB_NODES];
  const int t = threadIdx.x;
  const int n0 = blockIdx.x * CB_NODES;

  if (t < CB_NODES) nb_s[t] = node_batch[n0 + t];
  __syncthreads();

  // stage a2T (transposed, bf16)
  for (int it = 0; it < 64; ++it) {
    int i = it * 256 + t;
    int n = i >> 7;      // node within block
    int k = i & 127;     // feature 0..127
    float v;
    if (k < FIN) v = msg[(size_t)(n0 + n) * FIN + k];
    else         v = x[(size_t)(n0 + n) * FIN + (k - FIN)];
    smem[k * 136 + n] = f2b(v);
  }
  __syncthreads();

  const int tx = t & 15;   // col group: cols tx*8..+7
  const int ty = t >> 4;   // node group: nodes ty*8..+7
  const int colbase = tx << 3;

  float acc[8][8];
#pragma unroll
  for (int i = 0; i < 8; ++i)
#pragma unroll
    for (int j = 0; j < 8; ++j) acc[i][j] = 0.f;

  auto kstep = [&](int kidx, const float* row) {
    ushort8 s8 = *(const ushort8*)(smem + kidx * 136 + (ty << 3));
    float av[8];
#pragma unroll
    for (int i = 0; i < 8; ++i) av[i] = b2f((unsigned short)s8[i]);
    float4 wa = *(const float4*)(row + colbase);
    float4 wb = *(const float4*)(row + colbase + 4);
    float wv[8] = {wa.x, wa.y, wa.z, wa.w, wb.x, wb.y, wb.z, wb.w};
#pragma unroll
    for (int i = 0; i < 8; ++i)
#pragma unroll
      for (int j = 0; j < 8; ++j) acc[i][j] = fmaf(av[i], wv[j], acc[i][j]);
  };
  for (int k = 0; k < FIN; ++k) kstep(k, Wl + k * HIDDEN);
  for (int k = 0; k < FIN; ++k) kstep(FIN + k, Wr + k * HIDDEN);

  // epilogue: bias + relu, write h (bf16) back into smem as h[n][j]
  float4 ba = *(const float4*)(bconv + colbase);
  float4 bb = *(const float4*)(bconv + colbase + 4);
  float bv[8] = {ba.x, ba.y, ba.z, ba.w, bb.x, bb.y, bb.z, bb.w};

  __syncthreads();  // everyone done reading a2T before overwrite
#pragma unroll
  for (int i = 0; i < 8; ++i) {
    int n = (ty << 3) + i;
    ushort8 hv;
#pragma unroll
    for (int j = 0; j < 8; ++j) {
      float hval = fmaxf(acc[i][j] + bv[j], 0.f);
      hv[j] = f2b(hval);
    }
    *(ushort8*)(smem + n * HIDDEN + colbase) = hv;
  }
  __syncthreads();

  // segmented pool over sorted node_batch: ~1 atomic per (segment, col)
  if (t < HIDDEN) {
    int j = t;
    float sum = 0.f;
    int cur = nb_s[0];
    for (int n = 0; n < CB_NODES; ++n) {
      int b = nb_s[n];
      if (b != cur) {
        unsafeAtomicAdd(&g[(size_t)cur * HIDDEN + j], sum);
        sum = 0.f;
        cur = b;
      }
      sum += b2f(smem[n * HIDDEN + j]);
    }
    unsafeAtomicAdd(&g[(size_t)cur * HIDDEN + j], sum);
  }
}

// ---------------------------------------------------------------------------
// K3: MLP head, one wave per subgraph.
// ---------------------------------------------------------------------------
__global__ __launch_bounds__(256) void k_head(const float* __restrict__ g,
                                              const float* __restrict__ W1,
                                              const float* __restrict__ b1,
                                              const float* __restrict__ W2,
                                              const float* __restrict__ b2,
                                              const float* __restrict__ wts,
                                              const int* __restrict__ sgb,
                                              float* __restrict__ egy,
                                              float* __restrict__ nrm) {
  int s = blockIdx.x * 4 + (threadIdx.x >> 6);
  int lane = threadIdx.x & 63;
  const float* grow = g + (size_t)s * HIDDEN;
  float acc0 = b1[lane];
  float acc1 = b1[lane + 64];
  for (int k = 0; k < HIDDEN; ++k) {
    float gk = grow[k];  // wave-uniform
    acc0 = fmaf(gk, W1[k * HIDDEN + lane], acc0);
    acc1 = fmaf(gk, W1[k * HIDDEN + 64 + lane], acc1);
  }
  float t0 = acc0 > 0.f ? acc0 : 0.01f * acc0;
  float t1 = acc1 > 0.f ? acc1 : 0.01f * acc1;
  float part = t0 * W2[lane] + t1 * W2[lane + 64];
#pragma unroll
  for (int off = 32; off > 0; off >>= 1) part += __shfl_down(part, off, 64);
  if (lane == 0) {
    float sval = part + b2[0];
    float w = wts[s];
    int grp = sgb[s];
    unsafeAtomicAdd(&egy[grp], sval * w);
    unsafeAtomicAdd(&nrm[grp], w);
  }
}

__global__ void k_final(const float* __restrict__ egy,
                        const float* __restrict__ nrm,
                        float* __restrict__ out) {
  int t = threadIdx.x;
  out[t] = egy[t] / nrm[t];
}

// ---------------------------------------------------------------------------
extern "C" void kernel_launch(void* const* d_in, const int* in_sizes, int n_in,
                              void* d_out, int out_size, void* d_ws, size_t ws_size,
                              hipStream_t stream) {
  const float* x   = (const float*)d_in[0];
  const int*   ei  = (const int*)d_in[1];
  const int*   nb  = (const int*)d_in[2];
  const float* wts = (const float*)d_in[3];
  const int*   sgb = (const int*)d_in[4];
  const float* Wl  = (const float*)d_in[5];
  const float* Wr  = (const float*)d_in[6];
  const float* bcv = (const float*)d_in[7];
  const float* W1  = (const float*)d_in[8];
  const float* b1  = (const float*)d_in[9];
  const float* W2  = (const float*)d_in[10];
  const float* b2  = (const float*)d_in[11];
  float* out = (float*)d_out;

  // ws layout (4B units), zeroed region first:
  //   cnt[NN] | g[NS*128] | egy[64] | nrm[64]   <- memset 0
  //   rowptr[NN+1] | cursor[NN] | bsum[2048] | bucket[NE] | msg[NN*64]
  int*   cnt    = (int*)d_ws;
  float* g      = (float*)(cnt + NN);
  float* egy    = g + (size_t)NS * HIDDEN;
  float* nrm    = egy + NG;
  int*   rowptr = (int*)(nrm + NG);
  int*   cursor = rowptr + NN + 1;
  int*   bsum   = cursor + NN;
  int*   bucket = bsum + 2048;
  float* msg    = (float*)(bucket + NE);

  size_t zero_bytes = ((size_t)NN + (size_t)NS * HIDDEN + 2 * NG) * 4;
  hipMemsetAsync(d_ws, 0, zero_bytes, stream);

  k_hist <<<NE / 256, 256, 0, stream>>>(ei, cnt);
  k_scan1<<<NN / 256, 256, 0, stream>>>(cnt, rowptr, bsum);
  k_scan2<<<1, 256, 0, stream>>>(bsum);
  k_scan3<<<NN / 256, 256, 0, stream>>>(rowptr, bsum, cursor);
  k_place<<<NE / 256, 256, 0, stream>>>(ei, cursor, bucket);
  k_aggregate<<<NN / 16, 256, 0, stream>>>(x, rowptr, bucket, msg);
  k_conv<<<NN / CB_NODES, 256, 0, stream>>>(msg, x, nb, Wl, Wr, bcv, g);
  k_head<<<NS / 4, 256, 0, stream>>>(g, W1, b1, W2, b2, wts, sgb, egy, nrm);
  k_final<<<1, 64, 0, stream>>>(egy, nrm, out);
}

// Round 4
// 736.866 us; speedup vs baseline: 3.3249x; 1.1817x over previous
//
#include <hip/hip_runtime.h>
#include <hip/hip_bf16.h>

#define NN 524288     // nodes
#define NE 2097152    // edges
#define NS 8192       // subgraphs
#define NG 64         // groups
#define FIN 64
#define HIDDEN 128

typedef __attribute__((ext_vector_type(8))) unsigned short ushort8;
typedef __attribute__((ext_vector_type(4))) unsigned short ushort4v;
typedef __attribute__((ext_vector_type(8))) short bf16x8;
typedef __attribute__((ext_vector_type(4))) float floatx4;

__device__ __forceinline__ unsigned short f2b(float f) {
  union { float f; unsigned int u; } c; c.f = f;
  unsigned int u = c.u;
  unsigned int r = (u + 0x7FFFu + ((u >> 16) & 1u)) >> 16;  // RNE
  return (unsigned short)r;
}
__device__ __forceinline__ float b2f(unsigned short b) {
  union { unsigned int u; float f; } c; c.u = ((unsigned int)b) << 16;
  return c.f;
}

// ---------------------------------------------------------------------------
// K0a: cast x -> bf16 (xb).  8 floats per thread.
// ---------------------------------------------------------------------------
__global__ __launch_bounds__(256) void k_cast(const float* __restrict__ x,
                                              unsigned short* __restrict__ xb) {
  size_t i = ((size_t)blockIdx.x * 256 + threadIdx.x) * 8;
  float4 v0 = *(const float4*)(x + i);
  float4 v1 = *(const float4*)(x + i + 4);
  ushort8 r;
  r[0] = f2b(v0.x); r[1] = f2b(v0.y); r[2] = f2b(v0.z); r[3] = f2b(v0.w);
  r[4] = f2b(v1.x); r[5] = f2b(v1.y); r[6] = f2b(v1.z); r[7] = f2b(v1.w);
  *(ushort8*)(xb + i) = r;
}

// K0b: build Wt[n][k] = bf16( k<64 ? Wl[k][n] : Wr[k-64][n] ), 128x128
__global__ __launch_bounds__(256) void k_prepw(const float* __restrict__ Wl,
                                               const float* __restrict__ Wr,
                                               unsigned short* __restrict__ Wt) {
  int i = blockIdx.x * 256 + threadIdx.x;  // 64 blocks -> 16384
  int n = i >> 7, k = i & 127;
  float v = (k < FIN) ? Wl[k * HIDDEN + n] : Wr[(k - FIN) * HIDDEN + n];
  Wt[n * HIDDEN + k] = f2b(v);
}

// ---------------------------------------------------------------------------
// CSR build: histogram -> scan -> place  (cursor doubles as rowptr/endptr)
// ---------------------------------------------------------------------------
__global__ __launch_bounds__(256) void k_hist(const int* __restrict__ ei,
                                              int* __restrict__ cnt) {
  int e = blockIdx.x * 256 + threadIdx.x;
  int dst = ei[NE + e];
  atomicAdd(&cnt[dst], 1);
}

__global__ __launch_bounds__(256) void k_scan1(const int* __restrict__ cnt,
                                               int* __restrict__ cursor,
                                               int* __restrict__ bsum) {
  __shared__ int s[256];
  int t = threadIdx.x;
  int i = blockIdx.x * 256 + t;
  int v = cnt[i];
  s[t] = v;
  __syncthreads();
  for (int off = 1; off < 256; off <<= 1) {
    int xv = 0;
    if (t >= off) xv = s[t - off];
    __syncthreads();
    s[t] += xv;
    __syncthreads();
  }
  cursor[i] = s[t] - v;               // exclusive within block
  if (t == 255) bsum[blockIdx.x] = s[255];
}

__global__ __launch_bounds__(256) void k_scan2(int* __restrict__ bsum) {
  __shared__ int s[256];
  __shared__ int carry_s;
  int t = threadIdx.x;
  if (t == 0) carry_s = 0;
  __syncthreads();
  for (int c = 0; c < 8; ++c) {
    int v = bsum[c * 256 + t];
    s[t] = v;
    __syncthreads();
    for (int off = 1; off < 256; off <<= 1) {
      int xv = 0;
      if (t >= off) xv = s[t - off];
      __syncthreads();
      s[t] += xv;
      __syncthreads();
    }
    int carry = carry_s;
    int incl = s[t];
    bsum[c * 256 + t] = carry + incl - v;  // exclusive + carry
    __syncthreads();
    if (t == 255) carry_s = carry + incl;
    __syncthreads();
  }
}

__global__ __launch_bounds__(256) void k_scan3(int* __restrict__ cursor,
                                               const int* __restrict__ bsum) {
  int i = blockIdx.x * 256 + threadIdx.x;
  cursor[i] += bsum[blockIdx.x];
}

__global__ __launch_bounds__(256) void k_place(const int* __restrict__ ei,
                                               int* __restrict__ cursor,
                                               int* __restrict__ bucket) {
  int e = blockIdx.x * 256 + threadIdx.x;
  int src = ei[e];
  int dst = ei[NE + e];
  int pos = atomicAdd(&cursor[dst], 1);
  bucket[pos] = src;
}

// ---------------------------------------------------------------------------
// Aggregate: one node per 16-lane group, bf16 gather (128B rows), fp32 regs.
// After k_place, cursor[n] == end of node n's range; start = cursor[n-1].
// ---------------------------------------------------------------------------
__global__ __launch_bounds__(256) void k_aggregate(const unsigned short* __restrict__ xb,
                                                   const int* __restrict__ endptr,
                                                   const int* __restrict__ bucket,
                                                   unsigned short* __restrict__ msgb) {
  const int t = threadIdx.x;
  const int grp = t >> 4;
  const int lane = t & 15;
  const int n = blockIdx.x * 16 + grp;
  const int rp1 = endptr[n];
  const int rp0 = (n == 0) ? 0 : endptr[n - 1];

  float a0[4] = {0.f, 0.f, 0.f, 0.f};
  float a1[4] = {0.f, 0.f, 0.f, 0.f};
  float a2[4] = {0.f, 0.f, 0.f, 0.f};
  float a3[4] = {0.f, 0.f, 0.f, 0.f};
  int e = rp0;
  for (; e + 3 < rp1; e += 4) {
    int s0 = bucket[e], s1 = bucket[e + 1], s2 = bucket[e + 2], s3 = bucket[e + 3];
    ushort4v v0 = *(const ushort4v*)(xb + (size_t)s0 * FIN + (lane << 2));
    ushort4v v1 = *(const ushort4v*)(xb + (size_t)s1 * FIN + (lane << 2));
    ushort4v v2 = *(const ushort4v*)(xb + (size_t)s2 * FIN + (lane << 2));
    ushort4v v3 = *(const ushort4v*)(xb + (size_t)s3 * FIN + (lane << 2));
#pragma unroll
    for (int j = 0; j < 4; ++j) {
      a0[j] += b2f(v0[j]); a1[j] += b2f(v1[j]);
      a2[j] += b2f(v2[j]); a3[j] += b2f(v3[j]);
    }
  }
  for (; e < rp1; ++e) {
    int s0 = bucket[e];
    ushort4v v0 = *(const ushort4v*)(xb + (size_t)s0 * FIN + (lane << 2));
#pragma unroll
    for (int j = 0; j < 4; ++j) a0[j] += b2f(v0[j]);
  }
  float rdeg = 1.f / fmaxf((float)(rp1 - rp0), 1.f);
  ushort4v r;
#pragma unroll
  for (int j = 0; j < 4; ++j)
    r[j] = f2b((a0[j] + a1[j] + a2[j] + a3[j]) * rdeg);
  *(ushort4v*)(msgb + (size_t)n * FIN + (lane << 2)) = r;
}

// ---------------------------------------------------------------------------
// K2: MFMA conv + pool.  Per block 128 nodes, [M=128,K=128]x[K=128,N=128].
// A in LDS [m][k] bf16 stride 136; B from global Wt[n][k] (L1-hot 32KB).
// mfma_f32_16x16x32_bf16: A[m=lane&15][k=quad*8+j]; B^T per-lane contiguous k;
// C/D col=lane&15, row=quad*4+reg.
// ---------------------------------------------------------------------------
#define CB_NODES 128
__global__ __launch_bounds__(256) void k_conv(const unsigned short* __restrict__ msgb,
                                              const unsigned short* __restrict__ xb,
                                              const int* __restrict__ node_batch,
                                              const unsigned short* __restrict__ Wt,
                                              const float* __restrict__ bconv,
                                              float* __restrict__ g) {
  __shared__ unsigned short As[128 * 136];  // A[m][k]; later reused as h[m][n]
  __shared__ int nb_s[CB_NODES];
  const int t = threadIdx.x;
  const int n0 = blockIdx.x * CB_NODES;

  if (t < CB_NODES) nb_s[t] = node_batch[n0 + t];

  // stage A: row n <- [msgb[n] | xb[n]]  (16 chunks of 8 bf16 per row)
#pragma unroll
  for (int it = 0; it < 8; ++it) {
    int i = it * 256 + t;
    int n = i >> 4;
    int c = i & 15;
    const unsigned short* src = (c < 8)
        ? msgb + (size_t)(n0 + n) * FIN + c * 8
        : xb + (size_t)(n0 + n) * FIN + (c - 8) * 8;
    *(ushort8*)(As + n * 136 + c * 8) = *(const ushort8*)src;
  }
  __syncthreads();

  const int wave = t >> 6;     // rows wave*32 .. +31
  const int lane = t & 63;
  const int l16 = lane & 15;
  const int quad = lane >> 4;

  floatx4 acc[2][8];
#pragma unroll
  for (int mt = 0; mt < 2; ++mt)
#pragma unroll
    for (int nt = 0; nt < 8; ++nt) acc[mt][nt] = (floatx4){0.f, 0.f, 0.f, 0.f};

  float bv[8];
#pragma unroll
  for (int nt = 0; nt < 8; ++nt) bv[nt] = bconv[nt * 16 + l16];

#pragma unroll
  for (int ks = 0; ks < 4; ++ks) {
    bf16x8 a0 = *(const bf16x8*)(As + (wave * 32 + l16) * 136 + ks * 32 + quad * 8);
    bf16x8 a1 = *(const bf16x8*)(As + (wave * 32 + 16 + l16) * 136 + ks * 32 + quad * 8);
#pragma unroll
    for (int nt = 0; nt < 8; ++nt) {
      bf16x8 b = *(const bf16x8*)(Wt + (size_t)(nt * 16 + l16) * HIDDEN + ks * 32 + quad * 8);
      acc[0][nt] = __builtin_amdgcn_mfma_f32_16x16x32_bf16(a0, b, acc[0][nt], 0, 0, 0);
      acc[1][nt] = __builtin_amdgcn_mfma_f32_16x16x32_bf16(a1, b, acc[1][nt], 0, 0, 0);
    }
  }

  // epilogue: bias+relu -> h bf16 into As (each wave overwrites only its rows)
#pragma unroll
  for (int mt = 0; mt < 2; ++mt)
#pragma unroll
    for (int nt = 0; nt < 8; ++nt) {
      int col = nt * 16 + l16;
#pragma unroll
      for (int r = 0; r < 4; ++r) {
        int row = wave * 32 + mt * 16 + quad * 4 + r;
        float hv = fmaxf(acc[mt][nt][r] + bv[nt], 0.f);
        As[row * 136 + col] = f2b(hv);
      }
    }
  __syncthreads();

  // segmented pool: 2 threads per col, 64 nodes each (sorted node_batch)
  {
    int j = t & 127;
    int half = t >> 7;
    int ns = half * 64, ne = ns + 64;
    float sum = 0.f;
    int cur = nb_s[ns];
    for (int n = ns; n < ne; ++n) {
      int b = nb_s[n];
      if (b != cur) {
        unsafeAtomicAdd(&g[(size_t)cur * HIDDEN + j], sum);
        sum = 0.f;
        cur = b;
      }
      sum += b2f(As[n * 136 + j]);
    }
    unsafeAtomicAdd(&g[(size_t)cur * HIDDEN + j], sum);
  }
}

// ---------------------------------------------------------------------------
// K3: MLP head, one wave per subgraph.
// ---------------------------------------------------------------------------
__global__ __launch_bounds__(256) void k_head(const float* __restrict__ g,
                                              const float* __restrict__ W1,
                                              const float* __restrict__ b1,
                                              const float* __restrict__ W2,
                                              const float* __restrict__ b2,
                                              const float* __restrict__ wts,
                                              const int* __restrict__ sgb,
                                              float* __restrict__ egy,
                                              float* __restrict__ nrm) {
  int s = blockIdx.x * 4 + (threadIdx.x >> 6);
  int lane = threadIdx.x & 63;
  const float* grow = g + (size_t)s * HIDDEN;
  float acc0 = b1[lane];
  float acc1 = b1[lane + 64];
  for (int k = 0; k < HIDDEN; ++k) {
    float gk = grow[k];  // wave-uniform
    acc0 = fmaf(gk, W1[k * HIDDEN + lane], acc0);
    acc1 = fmaf(gk, W1[k * HIDDEN + 64 + lane], acc1);
  }
  float t0 = acc0 > 0.f ? acc0 : 0.01f * acc0;
  float t1 = acc1 > 0.f ? acc1 : 0.01f * acc1;
  float part = t0 * W2[lane] + t1 * W2[lane + 64];
#pragma unroll
  for (int off = 32; off > 0; off >>= 1) part += __shfl_down(part, off, 64);
  if (lane == 0) {
    float sval = part + b2[0];
    float w = wts[s];
    int grp = sgb[s];
    unsafeAtomicAdd(&egy[grp], sval * w);
    unsafeAtomicAdd(&nrm[grp], w);
  }
}

__global__ void k_final(const float* __restrict__ egy,
                        const float* __restrict__ nrm,
                        float* __restrict__ out) {
  int t = threadIdx.x;
  out[t] = egy[t] / nrm[t];
}

// ---------------------------------------------------------------------------
extern "C" void kernel_launch(void* const* d_in, const int* in_sizes, int n_in,
                              void* d_out, int out_size, void* d_ws, size_t ws_size,
                              hipStream_t stream) {
  const float* x   = (const float*)d_in[0];
  const int*   ei  = (const int*)d_in[1];
  const int*   nb  = (const int*)d_in[2];
  const float* wts = (const float*)d_in[3];
  const int*   sgb = (const int*)d_in[4];
  const float* Wl  = (const float*)d_in[5];
  const float* Wr  = (const float*)d_in[6];
  const float* bcv = (const float*)d_in[7];
  const float* W1  = (const float*)d_in[8];
  const float* b1  = (const float*)d_in[9];
  const float* W2  = (const float*)d_in[10];
  const float* b2  = (const float*)d_in[11];
  float* out = (float*)d_out;

  // ws layout (4B units), zeroed region first:
  //   cnt[NN] | g[NS*128] | egy[64] | nrm[64]   <- memset 0
  //   cursor[NN] | bsum[2048] | bucket[NE] | xb[NN*64 bf16] | msgb[NN*64 bf16] | Wt[16384 bf16]
  int*   cnt    = (int*)d_ws;
  float* g      = (float*)(cnt + NN);
  float* egy    = g + (size_t)NS * HIDDEN;
  float* nrm    = egy + NG;
  int*   cursor = (int*)(nrm + NG);
  int*   bsum   = cursor + NN;
  int*   bucket = bsum + 2048;
  unsigned short* xb   = (unsigned short*)(bucket + NE);
  unsigned short* msgb = xb + (size_t)NN * FIN;
  unsigned short* Wt   = msgb + (size_t)NN * FIN;

  size_t zero_bytes = ((size_t)NN + (size_t)NS * HIDDEN + 2 * NG) * 4;
  hipMemsetAsync(d_ws, 0, zero_bytes, stream);

  k_cast <<<(NN * FIN) / (256 * 8), 256, 0, stream>>>(x, xb);
  k_prepw<<<64, 256, 0, stream>>>(Wl, Wr, Wt);
  k_hist <<<NE / 256, 256, 0, stream>>>(ei, cnt);
  k_scan1<<<NN / 256, 256, 0, stream>>>(cnt, cursor, bsum);
  k_scan2<<<1, 256, 0, stream>>>(bsum);
  k_scan3<<<NN / 256, 256, 0, stream>>>(cursor, bsum);
  k_place<<<NE / 256, 256, 0, stream>>>(ei, cursor, bucket);
  k_aggregate<<<NN / 16, 256, 0, stream>>>(xb, cursor, bucket, msgb);
  k_conv<<<NN / CB_NODES, 256, 0, stream>>>(msgb, xb, nb, Wt, bcv, g);
  k_head<<<NS / 4, 256, 0, stream>>>(g, W1, b1, W2, b2, wts, sgb, egy, nrm);
  k_final<<<1, 64, 0, stream>>>(egy, nrm, out);
}

// Round 5
// 540.469 us; speedup vs baseline: 4.5332x; 1.3634x over previous
//
#include <hip/hip_runtime.h>
#include <hip/hip_bf16.h>

#define NN 524288     // nodes
#define NE 2097152    // edges
#define NS 8192       // subgraphs
#define NG 64         // groups
#define FIN 64
#define HIDDEN 128

#define NB 512        // coarse bins (dst >> 10)
#define BIN_NODES 1024
#define CAP 4608      // bin capacity: mean 4096 + 8 sigma

typedef __attribute__((ext_vector_type(8))) unsigned short ushort8;
typedef __attribute__((ext_vector_type(4))) unsigned short ushort4v;
typedef __attribute__((ext_vector_type(8))) short bf16x8;
typedef __attribute__((ext_vector_type(4))) float floatx4;

__device__ __forceinline__ unsigned short f2b(float f) {
  union { float f; unsigned int u; } c; c.f = f;
  unsigned int u = c.u;
  unsigned int r = (u + 0x7FFFu + ((u >> 16) & 1u)) >> 16;  // RNE
  return (unsigned short)r;
}
__device__ __forceinline__ float b2f(unsigned short b) {
  union { unsigned int u; float f; } c; c.u = ((unsigned int)b) << 16;
  return c.f;
}

// ---------------------------------------------------------------------------
// K0a: cast x -> bf16 (xb).  8 floats per thread.
// ---------------------------------------------------------------------------
__global__ __launch_bounds__(256) void k_cast(const float* __restrict__ x,
                                              unsigned short* __restrict__ xb) {
  size_t i = ((size_t)blockIdx.x * 256 + threadIdx.x) * 8;
  float4 v0 = *(const float4*)(x + i);
  float4 v1 = *(const float4*)(x + i + 4);
  ushort8 r;
  r[0] = f2b(v0.x); r[1] = f2b(v0.y); r[2] = f2b(v0.z); r[3] = f2b(v0.w);
  r[4] = f2b(v1.x); r[5] = f2b(v1.y); r[6] = f2b(v1.z); r[7] = f2b(v1.w);
  *(ushort8*)(xb + i) = r;
}

// K0b: build Wt[n][k] = bf16( k<64 ? Wl[k][n] : Wr[k-64][n] ), 128x128
__global__ __launch_bounds__(256) void k_prepw(const float* __restrict__ Wl,
                                               const float* __restrict__ Wr,
                                               unsigned short* __restrict__ Wt) {
  int i = blockIdx.x * 256 + threadIdx.x;  // 64 blocks -> 16384
  int n = i >> 7, k = i & 127;
  float v = (k < FIN) ? Wl[k * HIDDEN + n] : Wr[(k - FIN) * HIDDEN + n];
  Wt[n * HIDDEN + k] = f2b(v);
}

// ---------------------------------------------------------------------------
// K1a: coarse binning.  Each block: 4096 edges, LDS hist over 512 bins,
// one chunk-reservation atomic per (block,bin), packed write into bin region.
// pack = (dst_local << 19) | src   (src < 2^19, dst_local < 2^10)
// ---------------------------------------------------------------------------
__global__ __launch_bounds__(256) void k_bin1(const int* __restrict__ ei,
                                              int* __restrict__ binCursor,
                                              unsigned int* __restrict__ pairs) {
  __shared__ unsigned int pk[4096];
  __shared__ unsigned short bn[4096];
  __shared__ int cnt[NB];
  __shared__ int base[NB];
  const int t = threadIdx.x;
  const int eBase = blockIdx.x * 4096;
  cnt[t] = 0; cnt[t + 256] = 0;
  __syncthreads();
#pragma unroll
  for (int i = 0; i < 16; ++i) {
    int j = i * 256 + t;
    int e = eBase + j;
    int src = ei[e];
    int dst = ei[NE + e];
    int bin = dst >> 10;
    pk[j] = ((unsigned int)(dst & 1023) << 19) | (unsigned int)src;
    bn[j] = (unsigned short)bin;
    atomicAdd(&cnt[bin], 1);
  }
  __syncthreads();
  {
    int c0 = cnt[t], c1 = cnt[t + 256];
    base[t]       = atomicAdd(&binCursor[t], c0);
    base[t + 256] = atomicAdd(&binCursor[t + 256], c1);
    cnt[t] = 0; cnt[t + 256] = 0;
  }
  __syncthreads();
#pragma unroll
  for (int i = 0; i < 16; ++i) {
    int j = i * 256 + t;
    int bin = bn[j];
    int ofs = atomicAdd(&cnt[bin], 1);
    pairs[(size_t)bin * CAP + base[bin] + ofs] = pk[j];
  }
}

// ---------------------------------------------------------------------------
// K1b: per-bin local CSR.  One block per bin: stage pairs to LDS, LDS hist of
// 1024 local nodes, LDS scan -> start offsets S[n + (n>>10)] (+sentinel),
// then place src in-place over the bin's pairs region via LDS cursors.
// ---------------------------------------------------------------------------
__global__ __launch_bounds__(256) void k_bin2(const int* __restrict__ binCursor,
                                              unsigned int* __restrict__ pairs,
                                              int* __restrict__ S) {
  __shared__ unsigned int pk[CAP];
  __shared__ int cnt[BIN_NODES];
  __shared__ int ps[256];
  const int t = threadIdx.x;
  const int b = blockIdx.x;
  int total = binCursor[b];
  if (total > CAP) total = CAP;   // statistical impossibility; guard LDS
  const int gbase = b * CAP;

  for (int i = t; i < total; i += 256) pk[i] = pairs[gbase + i];
  cnt[t] = 0; cnt[t + 256] = 0; cnt[t + 512] = 0; cnt[t + 768] = 0;
  __syncthreads();

  for (int i = t; i < total; i += 256) atomicAdd(&cnt[pk[i] >> 19], 1);
  __syncthreads();

  // scan: thread t owns local nodes 4t..4t+3
  int c0 = cnt[4 * t], c1 = cnt[4 * t + 1], c2 = cnt[4 * t + 2], c3 = cnt[4 * t + 3];
  int tot4 = c0 + c1 + c2 + c3;
  ps[t] = tot4;
  __syncthreads();
  for (int off = 1; off < 256; off <<= 1) {
    int v = 0;
    if (t >= off) v = ps[t - off];
    __syncthreads();
    ps[t] += v;
    __syncthreads();
  }
  int e0 = ps[t] - tot4;
  int e1 = e0 + c0, e2 = e1 + c1, e3 = e2 + c2;
  cnt[4 * t] = e0; cnt[4 * t + 1] = e1; cnt[4 * t + 2] = e2; cnt[4 * t + 3] = e3;
  int sidx = b * (BIN_NODES + 1) + 4 * t;
  S[sidx]     = gbase + e0;
  S[sidx + 1] = gbase + e1;
  S[sidx + 2] = gbase + e2;
  S[sidx + 3] = gbase + e3;
  if (t == 0) S[b * (BIN_NODES + 1) + BIN_NODES] = gbase + total;
  __syncthreads();

  for (int i = t; i < total; i += 256) {
    unsigned int p = pk[i];
    int dl = p >> 19;
    int ofs = atomicAdd(&cnt[dl], 1);
    pairs[gbase + ofs] = p & 0x7FFFFu;   // now holds src only
  }
}

// ---------------------------------------------------------------------------
// Aggregate: one node per 16-lane group, bf16 gather (128B rows), fp32 regs.
// Edge range of node n: S[n + (n>>10)] .. S[n + (n>>10) + 1]  (bucket==pairs).
// ---------------------------------------------------------------------------
__global__ __launch_bounds__(256) void k_aggregate(const unsigned short* __restrict__ xb,
                                                   const int* __restrict__ S,
                                                   const unsigned int* __restrict__ bucket,
                                                   unsigned short* __restrict__ msgb) {
  const int t = threadIdx.x;
  const int grp = t >> 4;
  const int lane = t & 15;
  const int n = blockIdx.x * 16 + grp;
  const int sidx = n + (n >> 10);
  const int rp0 = S[sidx];
  const int rp1 = S[sidx + 1];

  float a0[4] = {0.f, 0.f, 0.f, 0.f};
  float a1[4] = {0.f, 0.f, 0.f, 0.f};
  float a2[4] = {0.f, 0.f, 0.f, 0.f};
  float a3[4] = {0.f, 0.f, 0.f, 0.f};
  int e = rp0;
  for (; e + 3 < rp1; e += 4) {
    int s0 = bucket[e], s1 = bucket[e + 1], s2 = bucket[e + 2], s3 = bucket[e + 3];
    ushort4v v0 = *(const ushort4v*)(xb + (size_t)s0 * FIN + (lane << 2));
    ushort4v v1 = *(const ushort4v*)(xb + (size_t)s1 * FIN + (lane << 2));
    ushort4v v2 = *(const ushort4v*)(xb + (size_t)s2 * FIN + (lane << 2));
    ushort4v v3 = *(const ushort4v*)(xb + (size_t)s3 * FIN + (lane << 2));
#pragma unroll
    for (int j = 0; j < 4; ++j) {
      a0[j] += b2f(v0[j]); a1[j] += b2f(v1[j]);
      a2[j] += b2f(v2[j]); a3[j] += b2f(v3[j]);
    }
  }
  for (; e < rp1; ++e) {
    int s0 = bucket[e];
    ushort4v v0 = *(const ushort4v*)(xb + (size_t)s0 * FIN + (lane << 2));
#pragma unroll
    for (int j = 0; j < 4; ++j) a0[j] += b2f(v0[j]);
  }
  float rdeg = 1.f / fmaxf((float)(rp1 - rp0), 1.f);
  ushort4v r;
#pragma unroll
  for (int j = 0; j < 4; ++j)
    r[j] = f2b((a0[j] + a1[j] + a2[j] + a3[j]) * rdeg);
  *(ushort4v*)(msgb + (size_t)n * FIN + (lane << 2)) = r;
}

// ---------------------------------------------------------------------------
// K2: MFMA conv + pool.  Per block 128 nodes, [M=128,K=128]x[K=128,N=128].
// ---------------------------------------------------------------------------
#define CB_NODES 128
__global__ __launch_bounds__(256) void k_conv(const unsigned short* __restrict__ msgb,
                                              const unsigned short* __restrict__ xb,
                                              const int* __restrict__ node_batch,
                                              const unsigned short* __restrict__ Wt,
                                              const float* __restrict__ bconv,
                                              float* __restrict__ g) {
  __shared__ unsigned short As[128 * 136];  // A[m][k]; later reused as h[m][n]
  __shared__ int nb_s[CB_NODES];
  const int t = threadIdx.x;
  const int n0 = blockIdx.x * CB_NODES;

  if (t < CB_NODES) nb_s[t] = node_batch[n0 + t];

  // stage A: row n <- [msgb[n] | xb[n]]  (16 chunks of 8 bf16 per row)
#pragma unroll
  for (int it = 0; it < 8; ++it) {
    int i = it * 256 + t;
    int n = i >> 4;
    int c = i & 15;
    const unsigned short* src = (c < 8)
        ? msgb + (size_t)(n0 + n) * FIN + c * 8
        : xb + (size_t)(n0 + n) * FIN + (c - 8) * 8;
    *(ushort8*)(As + n * 136 + c * 8) = *(const ushort8*)src;
  }
  __syncthreads();

  const int wave = t >> 6;     // rows wave*32 .. +31
  const int lane = t & 63;
  const int l16 = lane & 15;
  const int quad = lane >> 4;

  floatx4 acc[2][8];
#pragma unroll
  for (int mt = 0; mt < 2; ++mt)
#pragma unroll
    for (int nt = 0; nt < 8; ++nt) acc[mt][nt] = (floatx4){0.f, 0.f, 0.f, 0.f};

  float bv[8];
#pragma unroll
  for (int nt = 0; nt < 8; ++nt) bv[nt] = bconv[nt * 16 + l16];

#pragma unroll
  for (int ks = 0; ks < 4; ++ks) {
    bf16x8 a0 = *(const bf16x8*)(As + (wave * 32 + l16) * 136 + ks * 32 + quad * 8);
    bf16x8 a1 = *(const bf16x8*)(As + (wave * 32 + 16 + l16) * 136 + ks * 32 + quad * 8);
#pragma unroll
    for (int nt = 0; nt < 8; ++nt) {
      bf16x8 b = *(const bf16x8*)(Wt + (size_t)(nt * 16 + l16) * HIDDEN + ks * 32 + quad * 8);
      acc[0][nt] = __builtin_amdgcn_mfma_f32_16x16x32_bf16(a0, b, acc[0][nt], 0, 0, 0);
      acc[1][nt] = __builtin_amdgcn_mfma_f32_16x16x32_bf16(a1, b, acc[1][nt], 0, 0, 0);
    }
  }

  // epilogue: bias+relu -> h bf16 into As (each wave overwrites only its rows)
#pragma unroll
  for (int mt = 0; mt < 2; ++mt)
#pragma unroll
    for (int nt = 0; nt < 8; ++nt) {
      int col = nt * 16 + l16;
#pragma unroll
      for (int r = 0; r < 4; ++r) {
        int row = wave * 32 + mt * 16 + quad * 4 + r;
        float hv = fmaxf(acc[mt][nt][r] + bv[nt], 0.f);
        As[row * 136 + col] = f2b(hv);
      }
    }
  __syncthreads();

  // segmented pool: 2 threads per col, 64 nodes each (sorted node_batch)
  {
    int j = t & 127;
    int half = t >> 7;
    int ns = half * 64, ne = ns + 64;
    float sum = 0.f;
    int cur = nb_s[ns];
    for (int n = ns; n < ne; ++n) {
      int b = nb_s[n];
      if (b != cur) {
        unsafeAtomicAdd(&g[(size_t)cur * HIDDEN + j], sum);
        sum = 0.f;
        cur = b;
      }
      sum += b2f(As[n * 136 + j]);
    }
    unsafeAtomicAdd(&g[(size_t)cur * HIDDEN + j], sum);
  }
}

// ---------------------------------------------------------------------------
// K3: MLP head, one wave per subgraph.
// ---------------------------------------------------------------------------
__global__ __launch_bounds__(256) void k_head(const float* __restrict__ g,
                                              const float* __restrict__ W1,
                                              const float* __restrict__ b1,
                                              const float* __restrict__ W2,
                                              const float* __restrict__ b2,
                                              const float* __restrict__ wts,
                                              const int* __restrict__ sgb,
                                              float* __restrict__ egy,
                                              float* __restrict__ nrm) {
  int s = blockIdx.x * 4 + (threadIdx.x >> 6);
  int lane = threadIdx.x & 63;
  const float* grow = g + (size_t)s * HIDDEN;
  float acc0 = b1[lane];
  float acc1 = b1[lane + 64];
  for (int k = 0; k < HIDDEN; ++k) {
    float gk = grow[k];  // wave-uniform
    acc0 = fmaf(gk, W1[k * HIDDEN + lane], acc0);
    acc1 = fmaf(gk, W1[k * HIDDEN + 64 + lane], acc1);
  }
  float t0 = acc0 > 0.f ? acc0 : 0.01f * acc0;
  float t1 = acc1 > 0.f ? acc1 : 0.01f * acc1;
  float part = t0 * W2[lane] + t1 * W2[lane + 64];
#pragma unroll
  for (int off = 32; off > 0; off >>= 1) part += __shfl_down(part, off, 64);
  if (lane == 0) {
    float sval = part + b2[0];
    float w = wts[s];
    int grp = sgb[s];
    unsafeAtomicAdd(&egy[grp], sval * w);
    unsafeAtomicAdd(&nrm[grp], w);
  }
}

__global__ void k_final(const float* __restrict__ egy,
                        const float* __restrict__ nrm,
                        float* __restrict__ out) {
  int t = threadIdx.x;
  out[t] = egy[t] / nrm[t];
}

// ---------------------------------------------------------------------------
extern "C" void kernel_launch(void* const* d_in, const int* in_sizes, int n_in,
                              void* d_out, int out_size, void* d_ws, size_t ws_size,
                              hipStream_t stream) {
  const float* x   = (const float*)d_in[0];
  const int*   ei  = (const int*)d_in[1];
  const int*   nb  = (const int*)d_in[2];
  const float* wts = (const float*)d_in[3];
  const int*   sgb = (const int*)d_in[4];
  const float* Wl  = (const float*)d_in[5];
  const float* Wr  = (const float*)d_in[6];
  const float* bcv = (const float*)d_in[7];
  const float* W1  = (const float*)d_in[8];
  const float* b1  = (const float*)d_in[9];
  const float* W2  = (const float*)d_in[10];
  const float* b2  = (const float*)d_in[11];
  float* out = (float*)d_out;

  // ws layout (4B units), zeroed region first:
  //   binCursor[512] | g[NS*128] | egy[64] | nrm[64]   <- memset 0
  //   S[512*1025] | pairs[512*4608] | xb[NN*64 bf16] | msgb[NN*64 bf16] | Wt[16384 bf16]
  int*   binCursor = (int*)d_ws;
  float* g         = (float*)(binCursor + NB);
  float* egy       = g + (size_t)NS * HIDDEN;
  float* nrm       = egy + NG;
  int*   S         = (int*)(nrm + NG);
  unsigned int* pairs = (unsigned int*)(S + NB * (BIN_NODES + 1));
  unsigned short* xb   = (unsigned short*)(pairs + (size_t)NB * CAP);
  unsigned short* msgb = xb + (size_t)NN * FIN;
  unsigned short* Wt   = msgb + (size_t)NN * FIN;

  size_t zero_bytes = ((size_t)NB + (size_t)NS * HIDDEN + 2 * NG) * 4;
  hipMemsetAsync(d_ws, 0, zero_bytes, stream);

  k_cast <<<(NN * FIN) / (256 * 8), 256, 0, stream>>>(x, xb);
  k_prepw<<<64, 256, 0, stream>>>(Wl, Wr, Wt);
  k_bin1 <<<NE / 4096, 256, 0, stream>>>(ei, binCursor, pairs);
  k_bin2 <<<NB, 256, 0, stream>>>(binCursor, pairs, S);
  k_aggregate<<<NN / 16, 256, 0, stream>>>(xb, S, pairs, msgb);
  k_conv<<<NN / CB_NODES, 256, 0, stream>>>(msgb, xb, nb, Wt, bcv, g);
  k_head<<<NS / 4, 256, 0, stream>>>(g, W1, b1, W2, b2, wts, sgb, egy, nrm);
  k_final<<<1, 64, 0, stream>>>(egy, nrm, out);
}

// Round 6
// 485.473 us; speedup vs baseline: 5.0467x; 1.1133x over previous
//
#include <hip/hip_runtime.h>
#include <hip/hip_bf16.h>

#define NN 524288     // nodes
#define NE 2097152    // edges
#define NS 8192       // subgraphs
#define NG 64         // groups
#define FIN 64
#define HIDDEN 128

#define NB 512        // coarse bins (dst >> 10)
#define BIN_NODES 1024
#define CAP 4608      // bin capacity: mean 4096 + 8 sigma

typedef __attribute__((ext_vector_type(8))) unsigned short ushort8;
typedef __attribute__((ext_vector_type(4))) unsigned short ushort4v;
typedef __attribute__((ext_vector_type(8))) short bf16x8;
typedef __attribute__((ext_vector_type(4))) float floatx4;

__device__ __forceinline__ unsigned short f2b(float f) {
  union { float f; unsigned int u; } c; c.f = f;
  unsigned int u = c.u;
  unsigned int r = (u + 0x7FFFu + ((u >> 16) & 1u)) >> 16;  // RNE
  return (unsigned short)r;
}
__device__ __forceinline__ float b2f(unsigned short b) {
  union { unsigned int u; float f; } c; c.u = ((unsigned int)b) << 16;
  return c.f;
}

// ---------------------------------------------------------------------------
// K0a: cast x -> bf16 (xb).  8 floats per thread.
// ---------------------------------------------------------------------------
__global__ __launch_bounds__(256) void k_cast(const float* __restrict__ x,
                                              unsigned short* __restrict__ xb) {
  size_t i = ((size_t)blockIdx.x * 256 + threadIdx.x) * 8;
  float4 v0 = *(const float4*)(x + i);
  float4 v1 = *(const float4*)(x + i + 4);
  ushort8 r;
  r[0] = f2b(v0.x); r[1] = f2b(v0.y); r[2] = f2b(v0.z); r[3] = f2b(v0.w);
  r[4] = f2b(v1.x); r[5] = f2b(v1.y); r[6] = f2b(v1.z); r[7] = f2b(v1.w);
  *(ushort8*)(xb + i) = r;
}

// K0b: build Wt[n][k] = bf16( k<64 ? Wl[k][n] : Wr[k-64][n] ), 128x128
__global__ __launch_bounds__(256) void k_prepw(const float* __restrict__ Wl,
                                               const float* __restrict__ Wr,
                                               unsigned short* __restrict__ Wt) {
  int i = blockIdx.x * 256 + threadIdx.x;  // 64 blocks -> 16384
  int n = i >> 7, k = i & 127;
  float v = (k < FIN) ? Wl[k * HIDDEN + n] : Wr[(k - FIN) * HIDDEN + n];
  Wt[n * HIDDEN + k] = f2b(v);
}

// ---------------------------------------------------------------------------
// K1a: coarse binning.  Each block: 4096 edges, LDS hist over 512 bins,
// one chunk-reservation atomic per (block,bin), packed write into bin region.
// pack = (dst_local << 19) | src   (src < 2^19, dst_local < 2^10)
// ---------------------------------------------------------------------------
__global__ __launch_bounds__(256) void k_bin1(const int* __restrict__ ei,
                                              int* __restrict__ binCursor,
                                              unsigned int* __restrict__ pairs) {
  __shared__ unsigned int pk[4096];
  __shared__ unsigned short bn[4096];
  __shared__ int cnt[NB];
  __shared__ int base[NB];
  const int t = threadIdx.x;
  const int eBase = blockIdx.x * 4096;
  cnt[t] = 0; cnt[t + 256] = 0;
  __syncthreads();
#pragma unroll
  for (int i = 0; i < 16; ++i) {
    int j = i * 256 + t;
    int e = eBase + j;
    int src = ei[e];
    int dst = ei[NE + e];
    int bin = dst >> 10;
    pk[j] = ((unsigned int)(dst & 1023) << 19) | (unsigned int)src;
    bn[j] = (unsigned short)bin;
    atomicAdd(&cnt[bin], 1);
  }
  __syncthreads();
  {
    int c0 = cnt[t], c1 = cnt[t + 256];
    base[t]       = atomicAdd(&binCursor[t], c0);
    base[t + 256] = atomicAdd(&binCursor[t + 256], c1);
    cnt[t] = 0; cnt[t + 256] = 0;
  }
  __syncthreads();
#pragma unroll
  for (int i = 0; i < 16; ++i) {
    int j = i * 256 + t;
    int bin = bn[j];
    int ofs = atomicAdd(&cnt[bin], 1);
    pairs[(size_t)bin * CAP + base[bin] + ofs] = pk[j];
  }
}

// ---------------------------------------------------------------------------
// K1b: per-bin local CSR.  One block per bin: stage pairs to LDS, LDS hist of
// 1024 local nodes, LDS scan -> start offsets S[n + (n>>10)] (+sentinel),
// then place src in-place over the bin's pairs region via LDS cursors.
// ---------------------------------------------------------------------------
__global__ __launch_bounds__(256) void k_bin2(const int* __restrict__ binCursor,
                                              unsigned int* __restrict__ pairs,
                                              int* __restrict__ S) {
  __shared__ unsigned int pk[CAP];
  __shared__ int cnt[BIN_NODES];
  __shared__ int ps[256];
  const int t = threadIdx.x;
  const int b = blockIdx.x;
  int total = binCursor[b];
  if (total > CAP) total = CAP;   // statistical impossibility; guard LDS
  const int gbase = b * CAP;

  for (int i = t; i < total; i += 256) pk[i] = pairs[gbase + i];
  cnt[t] = 0; cnt[t + 256] = 0; cnt[t + 512] = 0; cnt[t + 768] = 0;
  __syncthreads();

  for (int i = t; i < total; i += 256) atomicAdd(&cnt[pk[i] >> 19], 1);
  __syncthreads();

  // scan: thread t owns local nodes 4t..4t+3
  int c0 = cnt[4 * t], c1 = cnt[4 * t + 1], c2 = cnt[4 * t + 2], c3 = cnt[4 * t + 3];
  int tot4 = c0 + c1 + c2 + c3;
  ps[t] = tot4;
  __syncthreads();
  for (int off = 1; off < 256; off <<= 1) {
    int v = 0;
    if (t >= off) v = ps[t - off];
    __syncthreads();
    ps[t] += v;
    __syncthreads();
  }
  int e0 = ps[t] - tot4;
  int e1 = e0 + c0, e2 = e1 + c1, e3 = e2 + c2;
  cnt[4 * t] = e0; cnt[4 * t + 1] = e1; cnt[4 * t + 2] = e2; cnt[4 * t + 3] = e3;
  int sidx = b * (BIN_NODES + 1) + 4 * t;
  S[sidx]     = gbase + e0;
  S[sidx + 1] = gbase + e1;
  S[sidx + 2] = gbase + e2;
  S[sidx + 3] = gbase + e3;
  if (t == 0) S[b * (BIN_NODES + 1) + BIN_NODES] = gbase + total;
  __syncthreads();

  for (int i = t; i < total; i += 256) {
    unsigned int p = pk[i];
    int dl = p >> 19;
    int ofs = atomicAdd(&cnt[dl], 1);
    pairs[gbase + ofs] = p & 0x7FFFFu;   // now holds src only
  }
}

// ---------------------------------------------------------------------------
// Aggregate v2: one node per 8-lane group, 16B/lane gathers (full row = 8
// lanes x ushort8).  fp32 register accumulation, 4-edge unroll for MLP.
// Edge range of node n: S[n + (n>>10)] .. S[n + (n>>10) + 1]  (bucket==pairs).
// ---------------------------------------------------------------------------
__global__ __launch_bounds__(256) void k_aggregate(const unsigned short* __restrict__ xb,
                                                   const int* __restrict__ S,
                                                   const unsigned int* __restrict__ bucket,
                                                   unsigned short* __restrict__ msgb) {
  const int t = threadIdx.x;
  const int grp = t >> 3;       // 0..31: node within block
  const int lane = t & 7;       // ushort8 slot within row
  const int n = blockIdx.x * 32 + grp;
  const int sidx = n + (n >> 10);
  const int rp0 = S[sidx];
  const int rp1 = S[sidx + 1];

  float a0[8] = {0,0,0,0,0,0,0,0};
  float a1[8] = {0,0,0,0,0,0,0,0};
  float a2[8] = {0,0,0,0,0,0,0,0};
  float a3[8] = {0,0,0,0,0,0,0,0};
  int e = rp0;
  for (; e + 3 < rp1; e += 4) {
    int s0 = bucket[e], s1 = bucket[e + 1], s2 = bucket[e + 2], s3 = bucket[e + 3];
    ushort8 v0 = *(const ushort8*)(xb + (size_t)s0 * FIN + (lane << 3));
    ushort8 v1 = *(const ushort8*)(xb + (size_t)s1 * FIN + (lane << 3));
    ushort8 v2 = *(const ushort8*)(xb + (size_t)s2 * FIN + (lane << 3));
    ushort8 v3 = *(const ushort8*)(xb + (size_t)s3 * FIN + (lane << 3));
#pragma unroll
    for (int j = 0; j < 8; ++j) {
      a0[j] += b2f(v0[j]); a1[j] += b2f(v1[j]);
      a2[j] += b2f(v2[j]); a3[j] += b2f(v3[j]);
    }
  }
  for (; e < rp1; ++e) {
    int s0 = bucket[e];
    ushort8 v0 = *(const ushort8*)(xb + (size_t)s0 * FIN + (lane << 3));
#pragma unroll
    for (int j = 0; j < 8; ++j) a0[j] += b2f(v0[j]);
  }
  float rdeg = 1.f / fmaxf((float)(rp1 - rp0), 1.f);
  ushort8 r;
#pragma unroll
  for (int j = 0; j < 8; ++j)
    r[j] = f2b((a0[j] + a1[j] + a2[j] + a3[j]) * rdeg);
  *(ushort8*)(msgb + (size_t)n * FIN + (lane << 3)) = r;
}

// ---------------------------------------------------------------------------
// K2: MFMA conv + pool.  Per block 128 nodes, [M=128,K=128]x[K=128,N=128].
// v2: BOTH A and B staged in LDS -> compiler emits fine-grained lgkmcnt for
// ds_read->MFMA (no vmcnt stalls in the inner loop).  LDS ~70KB, 2 blocks/CU.
// ---------------------------------------------------------------------------
#define CB_NODES 128
__global__ __launch_bounds__(256) void k_conv(const unsigned short* __restrict__ msgb,
                                              const unsigned short* __restrict__ xb,
                                              const int* __restrict__ node_batch,
                                              const unsigned short* __restrict__ Wt,
                                              const float* __restrict__ bconv,
                                              float* __restrict__ g) {
  __shared__ unsigned short As[128 * 136];  // A[m][k]; later reused as h[m][n]
  __shared__ unsigned short Ws[128 * 136];  // B[n][k]
  __shared__ int nb_s[CB_NODES];
  const int t = threadIdx.x;
  const int n0 = blockIdx.x * CB_NODES;

  if (t < CB_NODES) nb_s[t] = node_batch[n0 + t];

  // stage A: row n <- [msgb[n] | xb[n]]; stage B: row n <- Wt[n]
#pragma unroll
  for (int it = 0; it < 8; ++it) {
    int i = it * 256 + t;
    int n = i >> 4;
    int c = i & 15;
    const unsigned short* src = (c < 8)
        ? msgb + (size_t)(n0 + n) * FIN + c * 8
        : xb + (size_t)(n0 + n) * FIN + (c - 8) * 8;
    *(ushort8*)(As + n * 136 + c * 8) = *(const ushort8*)src;
    *(ushort8*)(Ws + n * 136 + c * 8) = *(const ushort8*)(Wt + n * HIDDEN + c * 8);
  }
  __syncthreads();

  const int wave = t >> 6;     // rows wave*32 .. +31
  const int lane = t & 63;
  const int l16 = lane & 15;
  const int quad = lane >> 4;

  floatx4 acc[2][8];
#pragma unroll
  for (int mt = 0; mt < 2; ++mt)
#pragma unroll
    for (int nt = 0; nt < 8; ++nt) acc[mt][nt] = (floatx4){0.f, 0.f, 0.f, 0.f};

  float bv[8];
#pragma unroll
  for (int nt = 0; nt < 8; ++nt) bv[nt] = bconv[nt * 16 + l16];

#pragma unroll
  for (int ks = 0; ks < 4; ++ks) {
    bf16x8 a0 = *(const bf16x8*)(As + (wave * 32 + l16) * 136 + ks * 32 + quad * 8);
    bf16x8 a1 = *(const bf16x8*)(As + (wave * 32 + 16 + l16) * 136 + ks * 32 + quad * 8);
#pragma unroll
    for (int nt = 0; nt < 8; ++nt) {
      bf16x8 b = *(const bf16x8*)(Ws + (nt * 16 + l16) * 136 + ks * 32 + quad * 8);
      acc[0][nt] = __builtin_amdgcn_mfma_f32_16x16x32_bf16(a0, b, acc[0][nt], 0, 0, 0);
      acc[1][nt] = __builtin_amdgcn_mfma_f32_16x16x32_bf16(a1, b, acc[1][nt], 0, 0, 0);
    }
  }

  // epilogue: bias+relu -> h bf16 into As (each wave overwrites only its rows)
#pragma unroll
  for (int mt = 0; mt < 2; ++mt)
#pragma unroll
    for (int nt = 0; nt < 8; ++nt) {
      int col = nt * 16 + l16;
#pragma unroll
      for (int r = 0; r < 4; ++r) {
        int row = wave * 32 + mt * 16 + quad * 4 + r;
        float hv = fmaxf(acc[mt][nt][r] + bv[nt], 0.f);
        As[row * 136 + col] = f2b(hv);
      }
    }
  __syncthreads();

  // segmented pool: 2 threads per col, 64 nodes each (sorted node_batch)
  {
    int j = t & 127;
    int half = t >> 7;
    int ns = half * 64, ne = ns + 64;
    float sum = 0.f;
    int cur = nb_s[ns];
    for (int n = ns; n < ne; ++n) {
      int b = nb_s[n];
      if (b != cur) {
        unsafeAtomicAdd(&g[(size_t)cur * HIDDEN + j], sum);
        sum = 0.f;
        cur = b;
      }
      sum += b2f(As[n * 136 + j]);
    }
    unsafeAtomicAdd(&g[(size_t)cur * HIDDEN + j], sum);
  }
}

// ---------------------------------------------------------------------------
// K3: MLP head, one wave per subgraph.
// ---------------------------------------------------------------------------
__global__ __launch_bounds__(256) void k_head(const float* __restrict__ g,
                                              const float* __restrict__ W1,
                                              const float* __restrict__ b1,
                                              const float* __restrict__ W2,
                                              const float* __restrict__ b2,
                                              const float* __restrict__ wts,
                                              const int* __restrict__ sgb,
                                              float* __restrict__ egy,
                                              float* __restrict__ nrm) {
  int s = blockIdx.x * 4 + (threadIdx.x >> 6);
  int lane = threadIdx.x & 63;
  const float* grow = g + (size_t)s * HIDDEN;
  float acc0 = b1[lane];
  float acc1 = b1[lane + 64];
  for (int k = 0; k < HIDDEN; ++k) {
    float gk = grow[k];  // wave-uniform
    acc0 = fmaf(gk, W1[k * HIDDEN + lane], acc0);
    acc1 = fmaf(gk, W1[k * HIDDEN + 64 + lane], acc1);
  }
  float t0 = acc0 > 0.f ? acc0 : 0.01f * acc0;
  float t1 = acc1 > 0.f ? acc1 : 0.01f * acc1;
  float part = t0 * W2[lane] + t1 * W2[lane + 64];
#pragma unroll
  for (int off = 32; off > 0; off >>= 1) part += __shfl_down(part, off, 64);
  if (lane == 0) {
    float sval = part + b2[0];
    float w = wts[s];
    int grp = sgb[s];
    unsafeAtomicAdd(&egy[grp], sval * w);
    unsafeAtomicAdd(&nrm[grp], w);
  }
}

__global__ void k_final(const float* __restrict__ egy,
                        const float* __restrict__ nrm,
                        float* __restrict__ out) {
  int t = threadIdx.x;
  out[t] = egy[t] / nrm[t];
}

// ---------------------------------------------------------------------------
extern "C" void kernel_launch(void* const* d_in, const int* in_sizes, int n_in,
                              void* d_out, int out_size, void* d_ws, size_t ws_size,
                              hipStream_t stream) {
  const float* x   = (const float*)d_in[0];
  const int*   ei  = (const int*)d_in[1];
  const int*   nb  = (const int*)d_in[2];
  const float* wts = (const float*)d_in[3];
  const int*   sgb = (const int*)d_in[4];
  const float* Wl  = (const float*)d_in[5];
  const float* Wr  = (const float*)d_in[6];
  const float* bcv = (const float*)d_in[7];
  const float* W1  = (const float*)d_in[8];
  const float* b1  = (const float*)d_in[9];
  const float* W2  = (const float*)d_in[10];
  const float* b2  = (const float*)d_in[11];
  float* out = (float*)d_out;

  // ws layout (4B units), zeroed region first:
  //   binCursor[512] | g[NS*128] | egy[64] | nrm[64]   <- memset 0
  //   S[512*1025] | pairs[512*4608] | xb[NN*64 bf16] | msgb[NN*64 bf16] | Wt[16384 bf16]
  int*   binCursor = (int*)d_ws;
  float* g         = (float*)(binCursor + NB);
  float* egy       = g + (size_t)NS * HIDDEN;
  float* nrm       = egy + NG;
  int*   S         = (int*)(nrm + NG);
  unsigned int* pairs = (unsigned int*)(S + NB * (BIN_NODES + 1));
  unsigned short* xb   = (unsigned short*)(pairs + (size_t)NB * CAP);
  unsigned short* msgb = xb + (size_t)NN * FIN;
  unsigned short* Wt   = msgb + (size_t)NN * FIN;

  size_t zero_bytes = ((size_t)NB + (size_t)NS * HIDDEN + 2 * NG) * 4;
  hipMemsetAsync(d_ws, 0, zero_bytes, stream);

  k_cast <<<(NN * FIN) / (256 * 8), 256, 0, stream>>>(x, xb);
  k_prepw<<<64, 256, 0, stream>>>(Wl, Wr, Wt);
  k_bin1 <<<NE / 4096, 256, 0, stream>>>(ei, binCursor, pairs);
  k_bin2 <<<NB, 256, 0, stream>>>(binCursor, pairs, S);
  k_aggregate<<<NN / 32, 256, 0, stream>>>(xb, S, pairs, msgb);
  k_conv<<<NN / CB_NODES, 256, 0, stream>>>(msgb, xb, nb, Wt, bcv, g);
  k_head<<<NS / 4, 256, 0, stream>>>(g, W1, b1, W2, b2, wts, sgb, egy, nrm);
  k_final<<<1, 64, 0, stream>>>(egy, nrm, out);
}